// Round 15
// baseline (983.718 us; speedup 1.0000x reference)
//
#include <hip/hip_runtime.h>
#include <hip/hip_bf16.h>
#include <hip/hip_cooperative_groups.h>

namespace cg = cooperative_groups;

#define N_NODES 20000
#define N_EDGES 320000
#define HID 256
#define NQ 5000            // nodes per quarter (histogram privatization)
#define ECHUNK 20000       // edges per chunk (16 chunks)
#define PREP_BLOCKS 256
#define GEMM_ROLES (313 * 4 * 2)

typedef __attribute__((ext_vector_type(8))) short bf16x8;   // MFMA A/B frag
typedef __attribute__((ext_vector_type(4))) float f32x4;    // MFMA C/D frag
typedef __attribute__((ext_vector_type(8))) unsigned short us8;  // 16B row chunk

__device__ __forceinline__ float bf2f(ushort u) {
  union { unsigned int i; float f; } v; v.i = ((unsigned int)u) << 16; return v.f;
}
__device__ __forceinline__ ushort f2bf(float f) {
  union { float f; unsigned int i; } v; v.f = f;
  unsigned int r = v.i + 0x7FFFu + ((v.i >> 16) & 1u);   // RNE
  return (ushort)(r >> 16);
}

// ===========================================================================
// prep_kernel (cooperative, 256 blocks x 1024 thr) -- VALIDATED r12.
// 44KB LDS -> 1 block/CU under the 64KB occupancy rule -> capacity 256 = grid.
// ===========================================================================
__global__ __launch_bounds__(1024) void prep_kernel(
    const void* e0, const void* e1, const void* x1,
    int* cnt0, int* cnt1, int* rp0, int* rp1,
    float* dinv0, float* dinv1,
    unsigned int* eg0, unsigned int* eg1,
    float* t0, float* t1, int* flags) {
  cg::grid_group grid = cg::this_grid();
  __shared__ int hist[NQ];
  __shared__ int base[NQ];
  __shared__ int sd[1024];
  __shared__ int dw, dz;
  int bx = blockIdx.x, tid = threadIdx.x;

  int idx = bx * 1024 + tid;
  if (idx < N_NODES) { cnt0[idx] = 0; cnt1[idx] = 0; t0[idx] = 0.f; t1[idx] = 0.f; }
  if (bx == PREP_BLOCKS - 1) {
    if (tid == 0) { dw = 0; dz = 0; }
    __syncthreads();
    if (tid < 256) {
      const ushort* xu = (const ushort*)x1;
      int wild = 0;
#pragma unroll
      for (int k = 0; k < 4; k++) {
        ushort u = xu[tid * 4 + k];
        int ex = (u >> 7) & 0xFF;
        if (ex >= 0x90) wild++;
      }
      if (wild) atomicAdd(&dw, wild);
      if (((const int*)e0)[tid * 2 + 1] != 0) atomicAdd(&dz, 1);
    }
    __syncthreads();
    if (tid == 0) { flags[0] = (dw > 64) ? 1 : 0; flags[1] = (dz < 8) ? 1 : 0; }
  }
  grid.sync();

  bool w64 = flags[1] != 0;
  int role = (bx < 128) ? bx : bx - 128;
  int branch = role & 1;
  int lo = ((role >> 1) & 3) * NQ;
  int ebeg = (role >> 3) * ECHUNK;
  const void* e = branch ? e1 : e0;
  const int* s32 = (const int*)e;
  const int* d32 = (const int*)e + N_EDGES;
  const long long* s64 = (const long long*)e;
  const long long* d64 = (const long long*)e + N_EDGES;

  if (bx < 128) {
    for (int k = tid; k < NQ; k += 1024) hist[k] = 0;
    __syncthreads();
    for (int i = ebeg + tid; i < ebeg + ECHUNK; i += 1024) {
      int d = w64 ? (int)d64[i] : d32[i];
      unsigned q = (unsigned)(d - lo);
      if (q < NQ) atomicAdd(&hist[q], 1);
    }
    __syncthreads();
    int* cnt = branch ? cnt1 : cnt0;
    for (int k = tid; k < NQ; k += 1024) {
      base[k] = atomicAdd(&cnt[lo + k], hist[k]);   // coalesced merge
      hist[k] = 0;                                  // reuse as local rank ctr
    }
  } else {
    float* tl = (float*)hist;
    for (int k = tid; k < NQ; k += 1024) tl[k] = 0.f;
  }
  grid.sync();

  if (bx == 128 || bx == 129) {
    int b = bx - 128;
    const int* cnt = b ? cnt1 : cnt0;
    int* rp = b ? rp1 : rp0;
    float* dinv = b ? dinv1 : dinv0;
    int bb = tid * 20;
    int pref[20];
    int run = 0;
#pragma unroll
    for (int k = 0; k < 20; k++) {
      int i = bb + k;
      int c = (i < N_NODES) ? cnt[i] : 0;
      if (i < N_NODES) dinv[i] = rsqrtf((float)c + 1.0f);
      run += c;
      pref[k] = run;
    }
    sd[tid] = run;
    __syncthreads();
    for (int off = 1; off < 1024; off <<= 1) {
      int v = (tid >= off) ? sd[tid - off] : 0;
      __syncthreads();
      sd[tid] += v;
      __syncthreads();
    }
    int offset = sd[tid] - run;
    if (tid == 0) rp[0] = 0;
#pragma unroll
    for (int k = 0; k < 20; k++) {
      int i = bb + k;
      if (i < N_NODES) rp[i + 1] = offset + pref[k];
    }
  }
  grid.sync();

  const float* dinv = branch ? dinv1 : dinv0;
  if (bx < 128) {
    const int* rp = branch ? rp1 : rp0;
    unsigned int* eg = branch ? eg1 : eg0;
    for (int i = ebeg + tid; i < ebeg + ECHUNK; i += 1024) {
      int d = w64 ? (int)d64[i] : d32[i];
      unsigned q = (unsigned)(d - lo);
      if (q < NQ) {
        int s = w64 ? (int)s64[i] : s32[i];
        int r = atomicAdd(&hist[q], 1);
        int slot = rp[d] + base[q] + r;
        eg[slot] = (unsigned int)s | ((unsigned int)f2bf(dinv[s] * dinv[d]) << 16);
      }
    }
  } else {
    float* tl = (float*)hist;
    float* t = branch ? t1 : t0;
    for (int i = ebeg + tid; i < ebeg + ECHUNK; i += 1024) {
      int s = w64 ? (int)s64[i] : s32[i];
      unsigned q = (unsigned)(s - lo);
      if (q < NQ) {
        int d = w64 ? (int)d64[i] : d32[i];
        atomicAdd(&tl[q], dinv[d]);
      }
    }
    __syncthreads();
    for (int k = tid; k < NQ; k += 1024)
      atomicAdd(&t[lo + k], tl[k]);                 // coalesced merge
  }
}

// ---------------------------------------------------------------------------
// gemm phase: 64x64 tile (r6-validated), flat LDS (As 64x42, Bs 64x42).
// Grid-strided on gridDim.x so any grid size is correct.
// ---------------------------------------------------------------------------
__device__ __forceinline__ void gemm_phase(
    const void* A0, const void* A1, const void* W,
    ushort* C0, ushort* C1, bool af32, bool wf32,
    ushort* As, ushort* Bs) {
  int tid = threadIdx.x;
  int wave = tid >> 6, lane = tid & 63;
  int quad = lane >> 4, r16 = lane & 15;
  int la_row = tid >> 2, la_off = (tid & 3) * 8;
  int bk = tid >> 3, bn0 = (tid & 7) * 8;
  for (int role = blockIdx.x; role < GEMM_ROLES; role += gridDim.x) {
    int z = role & 1;
    int n0 = ((role >> 1) & 3) * 64;
    int m0 = (role >> 3) * 64;
    const void* A = z ? A1 : A0;
    ushort* C = z ? C1 : C0;
    f32x4 acc0 = {0.f, 0.f, 0.f, 0.f}, acc1 = acc0, acc2 = acc0, acc3 = acc0;
    for (int k0 = 0; k0 < 256; k0 += 32) {
      int gr = m0 + la_row;
      if (af32) {
        float4 v0 = {0, 0, 0, 0}, v1 = v0;
        if (gr < N_NODES) {
          const float* pA = (const float*)A + gr * 256 + k0 + la_off;
          v0 = *(const float4*)pA;
          v1 = *(const float4*)(pA + 4);
        }
        ushort* d = &As[la_row * 42 + la_off];
        d[0] = f2bf(v0.x); d[1] = f2bf(v0.y); d[2] = f2bf(v0.z); d[3] = f2bf(v0.w);
        d[4] = f2bf(v1.x); d[5] = f2bf(v1.y); d[6] = f2bf(v1.z); d[7] = f2bf(v1.w);
      } else {
        int4 w0 = {0, 0, 0, 0};
        if (gr < N_NODES) w0 = *(const int4*)((const ushort*)A + gr * 256 + k0 + la_off);
        *(int4*)&As[la_row * 42 + la_off] = w0;
      }
      ushort wtmp[8];
      if (wf32) {
        const float* Wf = (const float*)W + (k0 + bk) * 256 + n0 + bn0;
        float4 u0 = *(const float4*)Wf;
        float4 u1 = *(const float4*)(Wf + 4);
        wtmp[0] = f2bf(u0.x); wtmp[1] = f2bf(u0.y); wtmp[2] = f2bf(u0.z); wtmp[3] = f2bf(u0.w);
        wtmp[4] = f2bf(u1.x); wtmp[5] = f2bf(u1.y); wtmp[6] = f2bf(u1.z); wtmp[7] = f2bf(u1.w);
      } else {
        *(int4*)wtmp = *(const int4*)((const ushort*)W + (k0 + bk) * 256 + n0 + bn0);
      }
#pragma unroll
      for (int j = 0; j < 8; j++) Bs[(bn0 + j) * 42 + bk] = wtmp[j];   // transpose
      __syncthreads();
      bf16x8 a  = *(const bf16x8*)&As[(wave * 16 + r16) * 42 + quad * 8];
      bf16x8 b0 = *(const bf16x8*)&Bs[r16 * 42 + quad * 8];
      bf16x8 b1 = *(const bf16x8*)&Bs[(16 + r16) * 42 + quad * 8];
      bf16x8 b2 = *(const bf16x8*)&Bs[(32 + r16) * 42 + quad * 8];
      bf16x8 b3 = *(const bf16x8*)&Bs[(48 + r16) * 42 + quad * 8];
      acc0 = __builtin_amdgcn_mfma_f32_16x16x32_bf16(a, b0, acc0, 0, 0, 0);
      acc1 = __builtin_amdgcn_mfma_f32_16x16x32_bf16(a, b1, acc1, 0, 0, 0);
      acc2 = __builtin_amdgcn_mfma_f32_16x16x32_bf16(a, b2, acc2, 0, 0, 0);
      acc3 = __builtin_amdgcn_mfma_f32_16x16x32_bf16(a, b3, acc3, 0, 0, 0);
      __syncthreads();
    }
    int orow = m0 + wave * 16 + quad * 4;
#pragma unroll
    for (int r = 0; r < 4; r++) {
      int gr = orow + r;
      if (gr < N_NODES) {
        ushort* cp = C + gr * 256 + n0 + r16;
        cp[0]  = f2bf(acc0[r]);
        cp[16] = f2bf(acc1[r]);
        cp[32] = f2bf(acc2[r]);
        cp[48] = f2bf(acc3[r]);
      }
    }
  }
}

// ---------------------------------------------------------------------------
// agg phase (r9/r11-validated body): wave = 2 independent halves, one node
// each; 8 full rows (64 lines) in flight. Grid-strided on gridDim.x.
// ---------------------------------------------------------------------------
__device__ __forceinline__ void agg_phase(
    const ushort* XW0, const ushort* XW1,
    const float* dinv0, const float* dinv1,
    const int* rp0, const int* rp1,
    const unsigned int* eg0, const unsigned int* eg1,
    const void* bias, ushort* H0, ushort* H1, bool wf32) {
  int tid = threadIdx.x;
  int wave = tid >> 6, lane = tid & 63;
  int half = lane >> 5;
  int fl = (lane & 31) * 8;
  for (int role = blockIdx.x; role < 5000; role += gridDim.x) {
    int b = role & 1;
    int nb = role >> 1;
    const ushort* XW = b ? XW1 : XW0;
    const float* dinv = b ? dinv1 : dinv0;
    const int* rp = b ? rp1 : rp0;
    const unsigned int* eg = b ? eg1 : eg0;
    ushort* H = b ? H1 : H0;
    int i = nb * 8 + wave * 2 + half;     // 2500*8 = 20000 exact
    float di = dinv[i];
    float selfw = di * di;
    us8 v = *(const us8*)(XW + i * 256 + fl);
    float acc[8], acc2[8];
#pragma unroll
    for (int k = 0; k < 8; k++) { acc[k] = selfw * bf2f(v[k]); acc2[k] = 0.f; }
    int e = rp[i], eend = rp[i + 1];
    for (; e + 4 <= eend; e += 4) {
      unsigned int p0 = eg[e], p1 = eg[e + 1], p2 = eg[e + 2], p3 = eg[e + 3];
      us8 r0 = *(const us8*)(XW + (p0 & 0xFFFFu) * 256 + fl);
      us8 r1 = *(const us8*)(XW + (p1 & 0xFFFFu) * 256 + fl);
      us8 r2 = *(const us8*)(XW + (p2 & 0xFFFFu) * 256 + fl);
      us8 r3 = *(const us8*)(XW + (p3 & 0xFFFFu) * 256 + fl);
      float w0 = bf2f((ushort)(p0 >> 16)), w1 = bf2f((ushort)(p1 >> 16));
      float w2 = bf2f((ushort)(p2 >> 16)), w3 = bf2f((ushort)(p3 >> 16));
#pragma unroll
      for (int k = 0; k < 8; k++) {
        acc[k]  += w0 * bf2f(r0[k]);
        acc2[k] += w1 * bf2f(r1[k]);
        acc[k]  += w2 * bf2f(r2[k]);
        acc2[k] += w3 * bf2f(r3[k]);
      }
    }
    for (; e < eend; e++) {
      unsigned int pp = eg[e];
      us8 r = *(const us8*)(XW + (pp & 0xFFFFu) * 256 + fl);
      float w = bf2f((ushort)(pp >> 16));
#pragma unroll
      for (int k = 0; k < 8; k++) acc[k] += w * bf2f(r[k]);
    }
    float bv[8];
    if (wf32) {
      const float* bf = (const float*)bias + fl;
      float4 c0 = *(const float4*)bf;
      float4 c1 = *(const float4*)(bf + 4);
      bv[0] = c0.x; bv[1] = c0.y; bv[2] = c0.z; bv[3] = c0.w;
      bv[4] = c1.x; bv[5] = c1.y; bv[6] = c1.z; bv[7] = c1.w;
    } else {
      us8 bb = *(const us8*)((const ushort*)bias + fl);
#pragma unroll
      for (int k = 0; k < 8; k++) bv[k] = bf2f(bb[k]);
    }
    us8 o;
#pragma unroll
    for (int k = 0; k < 8; k++)
      o[k] = f2bf(fmaxf(acc[k] + acc2[k] + bv[k], 0.f));
    *(us8*)(H + i * 256 + fl) = o;
  }
}

// colsum partials (128 roles, grid-strided); part = 4x256 floats in LDS.
__device__ __forceinline__ void colsum_phase(
    const ushort* h0, const ushort* h1,
    const float* dinv0, const float* dinv1,
    const float* t0, const float* t1, float* P, float* part) {
  int tid = threadIdx.x;
  int wave = tid >> 6, lane = tid & 63;
  for (int role = blockIdx.x; role < 128; role += gridDim.x) {
    int b = role & 1;
    int cx = role >> 1;
    const ushort* H = b ? h1 : h0;
    const float* dinv = b ? dinv1 : dinv0;
    const float* t = b ? t1 : t0;
    int wid = cx * 4 + wave;
    int f4 = lane * 4;
    float a0 = 0.f, a1 = 0.f, a2 = 0.f, a3 = 0.f;
    for (int j = wid; j < N_NODES; j += 256) {
      float dj = dinv[j];
      float c = dj * (t[j] + dj);
      ushort4 u = *(const ushort4*)(H + j * 256 + f4);
      a0 += c * bf2f(u.x); a1 += c * bf2f(u.y);
      a2 += c * bf2f(u.z); a3 += c * bf2f(u.w);
    }
    part[wave * 256 + f4 + 0] = a0; part[wave * 256 + f4 + 1] = a1;
    part[wave * 256 + f4 + 2] = a2; part[wave * 256 + f4 + 3] = a3;
    __syncthreads();
    int f = tid;
    float ssum = part[0 * 256 + f] + part[1 * 256 + f] + part[2 * 256 + f] + part[3 * 256 + f];
    P[(b * 64 + cx) * 256 + f] = ssum;
    __syncthreads();
  }
}

// final: pooled = ((s0+s1)@W3)/(2N)+b3 ; out = pooled@Wl + bl (block 0 only)
__device__ __forceinline__ void final_phase(
    const float* P, const void* W3, const void* b3,
    const void* Wl, const void* bl, void* out, bool wf32,
    float* vv, float* pooled) {
  if (blockIdx.x != 0) return;
  int t = threadIdx.x;
  float acc0 = 0.f, acc1 = 0.f;
  for (int b = 0; b < 64; b++) {
    acc0 += P[b * 256 + t];
    acc1 += P[(64 + b) * 256 + t];
  }
  vv[t] = acc0 + acc1;
  __syncthreads();
  float acc = 0.f;
  if (wf32) {
    const float* W3f = (const float*)W3;
    for (int f = 0; f < 256; f++) acc += vv[f] * W3f[f * 256 + t];
    pooled[t] = acc * (1.0f / (2.0f * N_NODES)) + ((const float*)b3)[t];
  } else {
    const ushort* W3b = (const ushort*)W3;
    for (int f = 0; f < 256; f++) acc += vv[f] * bf2f(W3b[f * 256 + t]);
    pooled[t] = acc * (1.0f / (2.0f * N_NODES)) + bf2f(((const ushort*)b3)[t]);
  }
  __syncthreads();
  if (t < 5) {
    float o;
    if (wf32) {
      o = ((const float*)bl)[t];
      for (int h = 0; h < 256; h++) o += pooled[h] * ((const float*)Wl)[h * 5 + t];
      ((float*)out)[t] = o;
    } else {
      o = bf2f(((const ushort*)bl)[t]);
      for (int h = 0; h < 256; h++) o += pooled[h] * bf2f(((const ushort*)Wl)[h * 5 + t]);
      ((ushort*)out)[t] = f2bf(o);
    }
  }
}

// ===========================================================================
// main_kernel (cooperative): phases overlay ONE 10.75KB LDS buffer (gemm
// As+Bs | colsum part | final vv+pooled) so >=5 blocks/CU fit even under the
// 64KB occupancy rule that rejected r13 (16.9KB x 4 > 64KB -> capacity 768 <
// grid 1024 -> silent launch failure). Grid is sized by the occupancy API at
// launch and all phases grid-stride on gridDim.x.
// ===========================================================================
__global__ __launch_bounds__(256, 4) void main_kernel(
    const void* x1, const void* x2,
    const void* W1, const void* b1, const void* W2, const void* b2,
    const void* W3, const void* b3, const void* Wl, const void* bl,
    ushort* xw0, ushort* xw1, ushort* h0, ushort* h1,
    const float* dinv0, const float* dinv1,
    const int* rp0, const int* rp1,
    const unsigned int* eg0, const unsigned int* eg1,
    const float* t0, const float* t1,
    float* P, void* out, const int* flags) {
  cg::grid_group grid = cg::this_grid();
  __shared__ long long smem_ll[1344];   // 10752 B, 8-aligned
  char* smem = (char*)smem_ll;
  ushort* As = (ushort*)smem;           // 64*42*2 = 5376 B
  ushort* Bs = (ushort*)(smem + 5376);  // 5376 B
  float* part = (float*)smem;           // 4096 B  (colsum)
  float* vv = (float*)smem;             // 1024 B  (final)
  float* pooled = (float*)(smem + 1024);
  bool wf32 = flags[0] != 0;

  gemm_phase(x1, x2, W1, xw0, xw1, wf32, wf32, As, Bs);
  grid.sync();
  agg_phase(xw0, xw1, dinv0, dinv1, rp0, rp1, eg0, eg1, b1, h0, h1, wf32);
  grid.sync();
  gemm_phase(h0, h1, W2, xw0, xw1, false, wf32, As, Bs);
  grid.sync();
  agg_phase(xw0, xw1, dinv0, dinv1, rp0, rp1, eg0, eg1, b2, h0, h1, wf32);
  grid.sync();
  colsum_phase(h0, h1, dinv0, dinv1, t0, t1, P, part);
  grid.sync();
  final_phase(P, W3, b3, Wl, bl, out, wf32, vv, pooled);
}

// --- Non-cooperative fallback wrappers (same phase bodies) ---
__global__ __launch_bounds__(256) void gemm_wrap(
    const void* A0, const void* A1, const void* W, ushort* C0, ushort* C1,
    int maybe_f32, const int* flags) {
  __shared__ ushort As[64 * 42];
  __shared__ ushort Bs[64 * 42];
  bool wf32 = flags[0] != 0;
  gemm_phase(A0, A1, W, C0, C1, maybe_f32 && wf32, wf32, As, Bs);
}
__global__ __launch_bounds__(256) void agg_wrap(
    const ushort* XW0, const ushort* XW1,
    const float* dinv0, const float* dinv1,
    const int* rp0, const int* rp1,
    const unsigned int* eg0, const unsigned int* eg1,
    const void* bias, ushort* H0, ushort* H1, const int* flags) {
  agg_phase(XW0, XW1, dinv0, dinv1, rp0, rp1, eg0, eg1, bias, H0, H1, flags[0] != 0);
}
__global__ __launch_bounds__(256) void colsum_wrap(
    const ushort* h0, const ushort* h1,
    const float* dinv0, const float* dinv1,
    const float* t0, const float* t1, float* P) {
  __shared__ float part[4 * 256];
  colsum_phase(h0, h1, dinv0, dinv1, t0, t1, P, part);
}
__global__ __launch_bounds__(256) void final_wrap(
    const float* P, const void* W3, const void* b3,
    const void* Wl, const void* bl, void* out, const int* flags) {
  __shared__ float vv[256];
  __shared__ float pooled[256];
  final_phase(P, W3, b3, Wl, bl, out, flags[0] != 0, vv, pooled);
}

extern "C" void kernel_launch(void* const* d_in, const int* in_sizes, int n_in,
                              void* d_out, int out_size, void* d_ws, size_t ws_size,
                              hipStream_t stream) {
  const void* x1 = d_in[0];
  const void* ei1 = d_in[1];
  const void* x2 = d_in[2];
  const void* ei2 = d_in[3];
  const void* W1 = d_in[4];
  const void* b1 = d_in[5];
  const void* W2 = d_in[6];
  const void* b2 = d_in[7];
  const void* W3 = d_in[8];
  const void* b3 = d_in[9];
  const void* Wl = d_in[10];
  const void* bl = d_in[11];
  void* out = d_out;

  char* p = (char*)d_ws;
  auto alloc = [&](size_t bytes) {
    char* r = p;
    p += (bytes + 255) & ~size_t(255);
    return r;
  };
  int* flags   = (int*)alloc(256);
  float* dinv0 = (float*)alloc(N_NODES * 4);
  float* dinv1 = (float*)alloc(N_NODES * 4);
  float* t0    = (float*)alloc(N_NODES * 4);
  float* t1    = (float*)alloc(N_NODES * 4);
  int* cnt0    = (int*)alloc(N_NODES * 4);
  int* cnt1    = (int*)alloc(N_NODES * 4);
  int* rp0     = (int*)alloc((N_NODES + 1) * 4);
  int* rp1     = (int*)alloc((N_NODES + 1) * 4);
  unsigned int* eg0 = (unsigned int*)alloc((size_t)N_EDGES * 4);
  unsigned int* eg1 = (unsigned int*)alloc((size_t)N_EDGES * 4);
  float* Pp    = (float*)alloc(2 * 64 * 256 * 4);
  ushort* xw0  = (ushort*)alloc((size_t)N_NODES * HID * 2);
  ushort* xw1  = (ushort*)alloc((size_t)N_NODES * HID * 2);
  ushort* h0   = (ushort*)alloc((size_t)N_NODES * HID * 2);
  ushort* h1   = (ushort*)alloc((size_t)N_NODES * HID * 2);

  // --- prep (1 cooperative launch; r12-validated config) ---
  {
    void* args[] = {(void*)&ei1, (void*)&ei2, (void*)&x1,
                    &cnt0, &cnt1, &rp0, &rp1, &dinv0, &dinv1,
                    &eg0, &eg1, &t0, &t1, &flags};
    hipLaunchCooperativeKernel((const void*)prep_kernel, dim3(PREP_BLOCKS),
                               dim3(1024), args, 0, stream);
  }

  // --- main: grid sized from occupancy API; checked; fallback path if coop
  //     launch is rejected (r13/r14 failed silently on capacity) ---
  int maxB = 0;
  hipError_t qerr = hipOccupancyMaxActiveBlocksPerMultiprocessor(
      &maxB, (const void*)main_kernel, 256, 0);
  int cap = (qerr == hipSuccess && maxB > 0) ? maxB * 256 : 512;
  int grid = cap < 1024 ? cap : 1024;
  hipError_t lerr = hipErrorUnknown;
  {
    void* args[] = {(void*)&x1, (void*)&x2,
                    (void*)&W1, (void*)&b1, (void*)&W2, (void*)&b2,
                    (void*)&W3, (void*)&b3, (void*)&Wl, (void*)&bl,
                    &xw0, &xw1, &h0, &h1, &dinv0, &dinv1, &rp0, &rp1,
                    &eg0, &eg1, &t0, &t1, &Pp, &out, &flags};
    lerr = hipLaunchCooperativeKernel((const void*)main_kernel, dim3(grid),
                                      dim3(256), args, 0, stream);
  }
  if (lerr != hipSuccess) {
    // Non-cooperative fallback: identical phase bodies, separate launches.
    gemm_wrap<<<dim3(GEMM_ROLES), 256, 0, stream>>>(x1, x2, W1, xw0, xw1, 1, flags);
    agg_wrap<<<dim3(5000), 256, 0, stream>>>(
        xw0, xw1, dinv0, dinv1, rp0, rp1, eg0, eg1, b1, h0, h1, flags);
    gemm_wrap<<<dim3(GEMM_ROLES), 256, 0, stream>>>(h0, h1, W2, xw0, xw1, 0, flags);
    agg_wrap<<<dim3(5000), 256, 0, stream>>>(
        xw0, xw1, dinv0, dinv1, rp0, rp1, eg0, eg1, b2, h0, h1, flags);
    colsum_wrap<<<dim3(128), 256, 0, stream>>>(h0, h1, dinv0, dinv1, t0, t1, Pp);
    final_wrap<<<dim3(1), 256, 0, stream>>>(Pp, W3, b3, Wl, bl, out, flags);
  }
}

// Round 16
// 432.426 us; speedup vs baseline: 2.2749x; 2.2749x over previous
//
#include <hip/hip_runtime.h>
#include <hip/hip_bf16.h>
#include <hip/hip_cooperative_groups.h>

namespace cg = cooperative_groups;

#define N_NODES 20000
#define N_EDGES 320000
#define HID 256
#define NQ 5000            // nodes per quarter (histogram privatization)
#define ECHUNK 20000       // edges per chunk (16 chunks)
#define PREP_BLOCKS 256
#define GEMM_ROLES (313 * 4 * 2)

typedef __attribute__((ext_vector_type(8))) short bf16x8;   // MFMA A/B frag
typedef __attribute__((ext_vector_type(4))) float f32x4;    // MFMA C/D frag
typedef __attribute__((ext_vector_type(8))) unsigned short us8;  // 16B row chunk

__device__ __forceinline__ float bf2f(ushort u) {
  union { unsigned int i; float f; } v; v.i = ((unsigned int)u) << 16; return v.f;
}
__device__ __forceinline__ ushort f2bf(float f) {
  union { float f; unsigned int i; } v; v.f = f;
  unsigned int r = v.i + 0x7FFFu + ((v.i >> 16) & 1u);   // RNE
  return (ushort)(r >> 16);
}

// ===========================================================================
// prep_kernel (cooperative, 256 blocks x 1024 thr) -- VALIDATED r12/r15.
// Replaces init+detect, count+rank, scan+dinv, eg-scatter+t (4 kernels + 3
// launch gaps in r11). 44KB LDS -> 1 block/CU -> capacity 256 = grid: safe.
// ===========================================================================
__global__ __launch_bounds__(1024) void prep_kernel(
    const void* e0, const void* e1, const void* x1,
    int* cnt0, int* cnt1, int* rp0, int* rp1,
    float* dinv0, float* dinv1,
    unsigned int* eg0, unsigned int* eg1,
    float* t0, float* t1, int* flags) {
  cg::grid_group grid = cg::this_grid();
  __shared__ int hist[NQ];
  __shared__ int base[NQ];
  __shared__ int sd[1024];
  __shared__ int dw, dz;
  int bx = blockIdx.x, tid = threadIdx.x;

  int idx = bx * 1024 + tid;
  if (idx < N_NODES) { cnt0[idx] = 0; cnt1[idx] = 0; t0[idx] = 0.f; t1[idx] = 0.f; }
  if (bx == PREP_BLOCKS - 1) {
    if (tid == 0) { dw = 0; dz = 0; }
    __syncthreads();
    if (tid < 256) {
      const ushort* xu = (const ushort*)x1;
      int wild = 0;
#pragma unroll
      for (int k = 0; k < 4; k++) {
        ushort u = xu[tid * 4 + k];
        int ex = (u >> 7) & 0xFF;
        if (ex >= 0x90) wild++;
      }
      if (wild) atomicAdd(&dw, wild);
      if (((const int*)e0)[tid * 2 + 1] != 0) atomicAdd(&dz, 1);
    }
    __syncthreads();
    if (tid == 0) { flags[0] = (dw > 64) ? 1 : 0; flags[1] = (dz < 8) ? 1 : 0; }
  }
  grid.sync();

  bool w64 = flags[1] != 0;
  int role = (bx < 128) ? bx : bx - 128;
  int branch = role & 1;
  int lo = ((role >> 1) & 3) * NQ;
  int ebeg = (role >> 3) * ECHUNK;
  const void* e = branch ? e1 : e0;
  const int* s32 = (const int*)e;
  const int* d32 = (const int*)e + N_EDGES;
  const long long* s64 = (const long long*)e;
  const long long* d64 = (const long long*)e + N_EDGES;

  if (bx < 128) {
    for (int k = tid; k < NQ; k += 1024) hist[k] = 0;
    __syncthreads();
    for (int i = ebeg + tid; i < ebeg + ECHUNK; i += 1024) {
      int d = w64 ? (int)d64[i] : d32[i];
      unsigned q = (unsigned)(d - lo);
      if (q < NQ) atomicAdd(&hist[q], 1);
    }
    __syncthreads();
    int* cnt = branch ? cnt1 : cnt0;
    for (int k = tid; k < NQ; k += 1024) {
      base[k] = atomicAdd(&cnt[lo + k], hist[k]);   // coalesced merge
      hist[k] = 0;                                  // reuse as local rank ctr
    }
  } else {
    float* tl = (float*)hist;
    for (int k = tid; k < NQ; k += 1024) tl[k] = 0.f;
  }
  grid.sync();

  if (bx == 128 || bx == 129) {
    int b = bx - 128;
    const int* cnt = b ? cnt1 : cnt0;
    int* rp = b ? rp1 : rp0;
    float* dinv = b ? dinv1 : dinv0;
    int bb = tid * 20;
    int pref[20];
    int run = 0;
#pragma unroll
    for (int k = 0; k < 20; k++) {
      int i = bb + k;
      int c = (i < N_NODES) ? cnt[i] : 0;
      if (i < N_NODES) dinv[i] = rsqrtf((float)c + 1.0f);
      run += c;
      pref[k] = run;
    }
    sd[tid] = run;
    __syncthreads();
    for (int off = 1; off < 1024; off <<= 1) {
      int v = (tid >= off) ? sd[tid - off] : 0;
      __syncthreads();
      sd[tid] += v;
      __syncthreads();
    }
    int offset = sd[tid] - run;
    if (tid == 0) rp[0] = 0;
#pragma unroll
    for (int k = 0; k < 20; k++) {
      int i = bb + k;
      if (i < N_NODES) rp[i + 1] = offset + pref[k];
    }
  }
  grid.sync();

  const float* dinv = branch ? dinv1 : dinv0;
  if (bx < 128) {
    const int* rp = branch ? rp1 : rp0;
    unsigned int* eg = branch ? eg1 : eg0;
    for (int i = ebeg + tid; i < ebeg + ECHUNK; i += 1024) {
      int d = w64 ? (int)d64[i] : d32[i];
      unsigned q = (unsigned)(d - lo);
      if (q < NQ) {
        int s = w64 ? (int)s64[i] : s32[i];
        int r = atomicAdd(&hist[q], 1);
        int slot = rp[d] + base[q] + r;
        eg[slot] = (unsigned int)s | ((unsigned int)f2bf(dinv[s] * dinv[d]) << 16);
      }
    }
  } else {
    float* tl = (float*)hist;
    float* t = branch ? t1 : t0;
    for (int i = ebeg + tid; i < ebeg + ECHUNK; i += 1024) {
      int s = w64 ? (int)s64[i] : s32[i];
      unsigned q = (unsigned)(s - lo);
      if (q < NQ) {
        int d = w64 ? (int)d64[i] : d32[i];
        atomicAdd(&tl[q], dinv[d]);
      }
    }
    __syncthreads();
    for (int k = tid; k < NQ; k += 1024)
      atomicAdd(&t[lo + k], tl[k]);                 // coalesced merge
  }
}

// ===========================================================================
// Phase bodies (proven correct inside r15's fused kernel) now run as
// STANDALONE kernels at full occupancy -- r15 post-mortem: fusing the heavy
// phases into one coop grid (4 blocks/CU) starved agg's gather MLP and
// serialized phase stragglers (884us vs ~200us split). Split is structural.
// ===========================================================================

// gemm: 64x64 tile, raw A (fp32/bf16 uniform branch) + raw W (coalesced read
// + LDS transpose, stride 42). One role per block (grid = 2504).
__global__ __launch_bounds__(256) void gemm_kernel(
    const void* __restrict__ A0, const void* __restrict__ A1,
    const void* __restrict__ W,
    ushort* __restrict__ C0, ushort* __restrict__ C1,
    int maybe_f32, const int* __restrict__ flags) {
  __shared__ ushort As[64][42];
  __shared__ ushort Bs[64][42];
  bool wf32 = flags[0] != 0;
  bool af32 = maybe_f32 && wf32;
  int tid = threadIdx.x;
  int wave = tid >> 6, lane = tid & 63;
  int quad = lane >> 4, r16 = lane & 15;
  int la_row = tid >> 2, la_off = (tid & 3) * 8;
  int bk = tid >> 3, bn0 = (tid & 7) * 8;
  int role = blockIdx.x;
  int z = role & 1;
  int n0 = ((role >> 1) & 3) * 64;
  int m0 = (role >> 3) * 64;
  const void* A = z ? A1 : A0;
  ushort* C = z ? C1 : C0;
  f32x4 acc0 = {0.f, 0.f, 0.f, 0.f}, acc1 = acc0, acc2 = acc0, acc3 = acc0;
  for (int k0 = 0; k0 < 256; k0 += 32) {
    int gr = m0 + la_row;
    if (af32) {
      float4 v0 = {0, 0, 0, 0}, v1 = v0;
      if (gr < N_NODES) {
        const float* pA = (const float*)A + gr * 256 + k0 + la_off;
        v0 = *(const float4*)pA;
        v1 = *(const float4*)(pA + 4);
      }
      ushort* d = &As[la_row][la_off];
      d[0] = f2bf(v0.x); d[1] = f2bf(v0.y); d[2] = f2bf(v0.z); d[3] = f2bf(v0.w);
      d[4] = f2bf(v1.x); d[5] = f2bf(v1.y); d[6] = f2bf(v1.z); d[7] = f2bf(v1.w);
    } else {
      int4 w0 = {0, 0, 0, 0};
      if (gr < N_NODES) w0 = *(const int4*)((const ushort*)A + gr * 256 + k0 + la_off);
      *(int4*)&As[la_row][la_off] = w0;
    }
    ushort wtmp[8];
    if (wf32) {
      const float* Wf = (const float*)W + (k0 + bk) * 256 + n0 + bn0;
      float4 u0 = *(const float4*)Wf;
      float4 u1 = *(const float4*)(Wf + 4);
      wtmp[0] = f2bf(u0.x); wtmp[1] = f2bf(u0.y); wtmp[2] = f2bf(u0.z); wtmp[3] = f2bf(u0.w);
      wtmp[4] = f2bf(u1.x); wtmp[5] = f2bf(u1.y); wtmp[6] = f2bf(u1.z); wtmp[7] = f2bf(u1.w);
    } else {
      *(int4*)wtmp = *(const int4*)((const ushort*)W + (k0 + bk) * 256 + n0 + bn0);
    }
#pragma unroll
    for (int j = 0; j < 8; j++) Bs[bn0 + j][bk] = wtmp[j];   // transpose scatter
    __syncthreads();
    bf16x8 a  = *(const bf16x8*)&As[wave * 16 + r16][quad * 8];
    bf16x8 b0 = *(const bf16x8*)&Bs[r16][quad * 8];
    bf16x8 b1 = *(const bf16x8*)&Bs[16 + r16][quad * 8];
    bf16x8 b2 = *(const bf16x8*)&Bs[32 + r16][quad * 8];
    bf16x8 b3 = *(const bf16x8*)&Bs[48 + r16][quad * 8];
    acc0 = __builtin_amdgcn_mfma_f32_16x16x32_bf16(a, b0, acc0, 0, 0, 0);
    acc1 = __builtin_amdgcn_mfma_f32_16x16x32_bf16(a, b1, acc1, 0, 0, 0);
    acc2 = __builtin_amdgcn_mfma_f32_16x16x32_bf16(a, b2, acc2, 0, 0, 0);
    acc3 = __builtin_amdgcn_mfma_f32_16x16x32_bf16(a, b3, acc3, 0, 0, 0);
    __syncthreads();
  }
  int orow = m0 + wave * 16 + quad * 4;
#pragma unroll
  for (int r = 0; r < 4; r++) {
    int gr = orow + r;
    if (gr < N_NODES) {
      ushort* cp = C + gr * 256 + n0 + r16;
      cp[0]  = f2bf(acc0[r]);
      cp[16] = f2bf(acc1[r]);
      cp[32] = f2bf(acc2[r]);
      cp[48] = f2bf(acc3[r]);
    }
  }
}

// agg: wave = 2 independent halves, one node each; 8 full rows (64 lines) in
// flight (r8/r9 lesson: line-level MLP is everything). Grid = 5000 x 256.
__global__ __launch_bounds__(256) void agg_kernel(
    const ushort* __restrict__ XW0, const ushort* __restrict__ XW1,
    const float* __restrict__ dinv0, const float* __restrict__ dinv1,
    const int* __restrict__ rp0, const int* __restrict__ rp1,
    const unsigned int* __restrict__ eg0, const unsigned int* __restrict__ eg1,
    const void* __restrict__ bias,
    ushort* __restrict__ H0, ushort* __restrict__ H1,
    const int* __restrict__ flags) {
  bool wf32 = flags[0] != 0;
  int tid = threadIdx.x;
  int wave = tid >> 6, lane = tid & 63;
  int half = lane >> 5;
  int fl = (lane & 31) * 8;
  int role = blockIdx.x;
  int b = role & 1;
  int nb = role >> 1;
  const ushort* XW = b ? XW1 : XW0;
  const float* dinv = b ? dinv1 : dinv0;
  const int* rp = b ? rp1 : rp0;
  const unsigned int* eg = b ? eg1 : eg0;
  ushort* H = b ? H1 : H0;
  int i = nb * 8 + wave * 2 + half;       // 2500*8 = 20000 exact
  float di = dinv[i];
  float selfw = di * di;
  us8 v = *(const us8*)(XW + i * 256 + fl);
  float acc[8], acc2[8];
#pragma unroll
  for (int k = 0; k < 8; k++) { acc[k] = selfw * bf2f(v[k]); acc2[k] = 0.f; }
  int e = rp[i], eend = rp[i + 1];
  for (; e + 4 <= eend; e += 4) {
    unsigned int p0 = eg[e], p1 = eg[e + 1], p2 = eg[e + 2], p3 = eg[e + 3];
    us8 r0 = *(const us8*)(XW + (p0 & 0xFFFFu) * 256 + fl);
    us8 r1 = *(const us8*)(XW + (p1 & 0xFFFFu) * 256 + fl);
    us8 r2 = *(const us8*)(XW + (p2 & 0xFFFFu) * 256 + fl);
    us8 r3 = *(const us8*)(XW + (p3 & 0xFFFFu) * 256 + fl);
    float w0 = bf2f((ushort)(p0 >> 16)), w1 = bf2f((ushort)(p1 >> 16));
    float w2 = bf2f((ushort)(p2 >> 16)), w3 = bf2f((ushort)(p3 >> 16));
#pragma unroll
    for (int k = 0; k < 8; k++) {
      acc[k]  += w0 * bf2f(r0[k]);
      acc2[k] += w1 * bf2f(r1[k]);
      acc[k]  += w2 * bf2f(r2[k]);
      acc2[k] += w3 * bf2f(r3[k]);
    }
  }
  for (; e < eend; e++) {
    unsigned int pp = eg[e];
    us8 r = *(const us8*)(XW + (pp & 0xFFFFu) * 256 + fl);
    float w = bf2f((ushort)(pp >> 16));
#pragma unroll
    for (int k = 0; k < 8; k++) acc[k] += w * bf2f(r[k]);
  }
  float bv[8];
  if (wf32) {
    const float* bf = (const float*)bias + fl;
    float4 c0 = *(const float4*)bf;
    float4 c1 = *(const float4*)(bf + 4);
    bv[0] = c0.x; bv[1] = c0.y; bv[2] = c0.z; bv[3] = c0.w;
    bv[4] = c1.x; bv[5] = c1.y; bv[6] = c1.z; bv[7] = c1.w;
  } else {
    us8 bb = *(const us8*)((const ushort*)bias + fl);
#pragma unroll
    for (int k = 0; k < 8; k++) bv[k] = bf2f(bb[k]);
  }
  us8 o;
#pragma unroll
  for (int k = 0; k < 8; k++)
    o[k] = f2bf(fmaxf(acc[k] + acc2[k] + bv[k], 0.f));
  *(us8*)(H + i * 256 + fl) = o;
}

// colsum partials: grid = (128) x 256; P[(b*64+cx)*256+f].
__global__ __launch_bounds__(256) void colsum_kernel(
    const ushort* __restrict__ h0, const ushort* __restrict__ h1,
    const float* __restrict__ dinv0, const float* __restrict__ dinv1,
    const float* __restrict__ t0, const float* __restrict__ t1,
    float* __restrict__ P) {
  __shared__ float part[4][256];
  int tid = threadIdx.x;
  int wave = tid >> 6, lane = tid & 63;
  int role = blockIdx.x;
  int b = role & 1;
  int cx = role >> 1;
  const ushort* H = b ? h1 : h0;
  const float* dinv = b ? dinv1 : dinv0;
  const float* t = b ? t1 : t0;
  int wid = cx * 4 + wave;
  int f4 = lane * 4;
  float a0 = 0.f, a1 = 0.f, a2 = 0.f, a3 = 0.f;
  for (int j = wid; j < N_NODES; j += 256) {
    float dj = dinv[j];
    float c = dj * (t[j] + dj);
    ushort4 u = *(const ushort4*)(H + j * 256 + f4);
    a0 += c * bf2f(u.x); a1 += c * bf2f(u.y);
    a2 += c * bf2f(u.z); a3 += c * bf2f(u.w);
  }
  part[wave][f4 + 0] = a0; part[wave][f4 + 1] = a1;
  part[wave][f4 + 2] = a2; part[wave][f4 + 3] = a3;
  __syncthreads();
  int f = tid;
  float ssum = part[0][f] + part[1][f] + part[2][f] + part[3][f];
  P[(b * 64 + cx) * 256 + f] = ssum;
}

// final: pooled = ((s0+s1)@W3)/(2N)+b3 ; out = pooled@Wl + bl
__global__ __launch_bounds__(256) void final_kernel(
    const float* __restrict__ P,
    const void* __restrict__ W3, const void* __restrict__ b3,
    const void* __restrict__ Wl, const void* __restrict__ bl,
    void* __restrict__ out, const int* __restrict__ flags) {
  __shared__ float vv[256];
  __shared__ float pooled[256];
  bool wf32 = flags[0] != 0;
  int t = threadIdx.x;
  float acc0 = 0.f, acc1 = 0.f;
  for (int b = 0; b < 64; b++) {
    acc0 += P[b * 256 + t];
    acc1 += P[(64 + b) * 256 + t];
  }
  vv[t] = acc0 + acc1;
  __syncthreads();
  float acc = 0.f;
  if (wf32) {
    const float* W3f = (const float*)W3;
    for (int f = 0; f < 256; f++) acc += vv[f] * W3f[f * 256 + t];
    pooled[t] = acc * (1.0f / (2.0f * N_NODES)) + ((const float*)b3)[t];
  } else {
    const ushort* W3b = (const ushort*)W3;
    for (int f = 0; f < 256; f++) acc += vv[f] * bf2f(W3b[f * 256 + t]);
    pooled[t] = acc * (1.0f / (2.0f * N_NODES)) + bf2f(((const ushort*)b3)[t]);
  }
  __syncthreads();
  if (t < 5) {
    float o;
    if (wf32) {
      o = ((const float*)bl)[t];
      for (int h = 0; h < 256; h++) o += pooled[h] * ((const float*)Wl)[h * 5 + t];
      ((float*)out)[t] = o;
    } else {
      o = bf2f(((const ushort*)bl)[t]);
      for (int h = 0; h < 256; h++) o += pooled[h] * bf2f(((const ushort*)Wl)[h * 5 + t]);
      ((ushort*)out)[t] = f2bf(o);
    }
  }
}

extern "C" void kernel_launch(void* const* d_in, const int* in_sizes, int n_in,
                              void* d_out, int out_size, void* d_ws, size_t ws_size,
                              hipStream_t stream) {
  const void* x1 = d_in[0];
  const void* ei1 = d_in[1];
  const void* x2 = d_in[2];
  const void* ei2 = d_in[3];
  const void* W1 = d_in[4];
  const void* b1 = d_in[5];
  const void* W2 = d_in[6];
  const void* b2 = d_in[7];
  const void* W3 = d_in[8];
  const void* b3 = d_in[9];
  const void* Wl = d_in[10];
  const void* bl = d_in[11];
  void* out = d_out;

  char* p = (char*)d_ws;
  auto alloc = [&](size_t bytes) {
    char* r = p;
    p += (bytes + 255) & ~size_t(255);
    return r;
  };
  int* flags   = (int*)alloc(256);
  float* dinv0 = (float*)alloc(N_NODES * 4);
  float* dinv1 = (float*)alloc(N_NODES * 4);
  float* t0    = (float*)alloc(N_NODES * 4);
  float* t1    = (float*)alloc(N_NODES * 4);
  int* cnt0    = (int*)alloc(N_NODES * 4);
  int* cnt1    = (int*)alloc(N_NODES * 4);
  int* rp0     = (int*)alloc((N_NODES + 1) * 4);
  int* rp1     = (int*)alloc((N_NODES + 1) * 4);
  unsigned int* eg0 = (unsigned int*)alloc((size_t)N_EDGES * 4);
  unsigned int* eg1 = (unsigned int*)alloc((size_t)N_EDGES * 4);
  float* Pp    = (float*)alloc(2 * 64 * 256 * 4);
  ushort* xw0  = (ushort*)alloc((size_t)N_NODES * HID * 2);
  ushort* xw1  = (ushort*)alloc((size_t)N_NODES * HID * 2);
  ushort* h0   = (ushort*)alloc((size_t)N_NODES * HID * 2);
  ushort* h1   = (ushort*)alloc((size_t)N_NODES * HID * 2);

  // --- prep (1 cooperative launch; r12/r15-validated; replaces 4 kernels) ---
  {
    void* args[] = {(void*)&ei1, (void*)&ei2, (void*)&x1,
                    &cnt0, &cnt1, &rp0, &rp1, &dinv0, &dinv1,
                    &eg0, &eg1, &t0, &t1, &flags};
    hipLaunchCooperativeKernel((const void*)prep_kernel, dim3(PREP_BLOCKS),
                               dim3(1024), args, 0, stream);
  }

  // --- main phases: standalone kernels at full occupancy (r15 post-mortem:
  //     fused coop grid starved agg; split is the right architecture) ---
  gemm_kernel<<<dim3(GEMM_ROLES), 256, 0, stream>>>(x1, x2, W1, xw0, xw1, 1, flags);
  agg_kernel<<<dim3(5000), 256, 0, stream>>>(
      xw0, xw1, dinv0, dinv1, rp0, rp1, eg0, eg1, b1, h0, h1, flags);
  gemm_kernel<<<dim3(GEMM_ROLES), 256, 0, stream>>>(h0, h1, W2, xw0, xw1, 0, flags);
  agg_kernel<<<dim3(5000), 256, 0, stream>>>(
      xw0, xw1, dinv0, dinv1, rp0, rp1, eg0, eg1, b2, h0, h1, flags);
  colsum_kernel<<<dim3(128), 256, 0, stream>>>(h0, h1, dinv0, dinv1, t0, t1, Pp);
  final_kernel<<<dim3(1), 256, 0, stream>>>(Pp, W3, b3, Wl, bl, out, flags);
}